// Round 1
// baseline (324.200 us; speedup 1.0000x reference)
//
#include <hip/hip_runtime.h>

// SpMM: out[b,m] = bias[m] + sum_{e: dst[e]==m} values[e] * x[b, src[e]]
// B=32, N=M=50000, E=1600000.
// v2 strategy: replace the 51.2M-fp32-atomic scatter (atomic-throughput-bound,
// WRITE_SIZE showed 204.8MB = E*128B) with an on-the-fly CSR build
// (histogram -> scan -> reorder) + per-dst register-accumulating gather that
// writes each out_t row exactly once (write traffic 204.8MB -> 6.4MB).

#define BATCH 32

// ---- transpose x (B,N) -> xt (N,B), LDS tiled ----
__global__ void k_transpose_x(const float* __restrict__ x, float* __restrict__ xt, int N) {
    __shared__ float tile[32][33];
    const int n0 = blockIdx.x * 32;
    const int tx = threadIdx.x;   // 0..31
    const int ty = threadIdx.y;   // 0..7
    #pragma unroll
    for (int k = 0; k < 4; ++k) {
        const int b = ty + 8 * k;
        const int n = n0 + tx;
        tile[tx][b] = (n < N) ? x[(size_t)b * N + n] : 0.0f;
    }
    __syncthreads();
    #pragma unroll
    for (int k = 0; k < 4; ++k) {
        const int n = n0 + ty + 8 * k;
        if (n < N) xt[(size_t)n * BATCH + tx] = tile[ty + 8 * k][tx];
    }
}

// ---- CSR build: zero counts ----
__global__ void k_zero_i32(int* __restrict__ p, int n) {
    const int i = blockIdx.x * blockDim.x + threadIdx.x;
    if (i < n) p[i] = 0;
}

// ---- CSR build: histogram of dst ----
__global__ void k_hist(const int* __restrict__ idx, int* __restrict__ counts, int E) {
    const int e = blockIdx.x * blockDim.x + threadIdx.x;
    if (e < E) atomicAdd(&counts[idx[E + e]], 1);
}

// ---- CSR build: block-local exclusive scan (1024/block) ----
__global__ __launch_bounds__(1024) void k_scan_local(const int* __restrict__ counts,
                                                     int* __restrict__ offsets,
                                                     int* __restrict__ bsums, int M) {
    __shared__ int s[1024];
    const int tid = threadIdx.x;
    const int i = blockIdx.x * 1024 + tid;
    const int v = (i < M) ? counts[i] : 0;
    s[tid] = v;
    __syncthreads();
    for (int off = 1; off < 1024; off <<= 1) {
        const int t = (tid >= off) ? s[tid - off] : 0;
        __syncthreads();
        s[tid] += t;
        __syncthreads();
    }
    if (i < M) offsets[i] = s[tid] - v;            // block-local exclusive
    if (tid == 1023) bsums[blockIdx.x] = s[1023];  // block total
}

// ---- CSR build: scan the (<=64) block sums; also write offsets[M] = E ----
__global__ void k_scan_bsums(const int* __restrict__ bsums, int* __restrict__ bprefix,
                             int* __restrict__ offsets, int nb, int M) {
    if (threadIdx.x == 0 && blockIdx.x == 0) {
        int run = 0;
        for (int i = 0; i < nb; ++i) { bprefix[i] = run; run += bsums[i]; }
        offsets[M] = run;  // == E
    }
}

// ---- CSR build: add block prefixes; init cursor = segment start ----
__global__ void k_scan_add(int* __restrict__ offsets, int* __restrict__ cursor,
                           const int* __restrict__ bprefix, int M) {
    const int i = blockIdx.x * blockDim.x + threadIdx.x;
    if (i < M) {
        const int o = offsets[i] + bprefix[i >> 10];
        offsets[i] = o;
        cursor[i] = o;
    }
}

// ---- CSR build: reorder edges into dst-grouped (src, val) pairs ----
__global__ void k_reorder(const int* __restrict__ idx, const float* __restrict__ values,
                          int* __restrict__ cursor, int2* __restrict__ sv, int E) {
    const int e = blockIdx.x * blockDim.x + threadIdx.x;
    if (e < E) {
        const int dst = idx[E + e];
        const int pos = atomicAdd(&cursor[dst], 1);
        sv[pos] = make_int2(idx[e], __float_as_int(values[e]));
    }
}

// ---- gather: one wave per dst; lanes 0..31 = batch, two half-waves split edges ----
__global__ __launch_bounds__(256) void k_gather(const int2* __restrict__ sv,
                                                const int* __restrict__ offsets,
                                                const float* __restrict__ xt,
                                                const float* __restrict__ bias,
                                                float* __restrict__ out_t, int M) {
    const int lane = threadIdx.x & 63;
    const int wid  = threadIdx.x >> 6;
    const int b    = lane & 31;
    const int half = lane >> 5;
    const int m = blockIdx.x * 4 + wid;
    if (m >= M) return;
    const int beg = offsets[m];
    const int end = offsets[m + 1];
    float acc = 0.0f;
    int i = beg + half;
    // stride-2 per half-wave, unrolled x2 -> up to 4 gathers in flight per wave
    for (; i + 2 < end; i += 4) {
        const int2 a = sv[i];
        const int2 c = sv[i + 2];
        acc += __int_as_float(a.y) * xt[(size_t)a.x * BATCH + b];
        acc += __int_as_float(c.y) * xt[(size_t)c.x * BATCH + b];
    }
    if (i < end) {
        const int2 a = sv[i];
        acc += __int_as_float(a.y) * xt[(size_t)a.x * BATCH + b];
    }
    acc += __shfl_xor(acc, 32, 64);  // combine the two half-waves
    if (half == 0) out_t[(size_t)m * BATCH + b] = acc + bias[m];
}

// ---- fallback (atomic) path kernels, used only if workspace is too small ----
__global__ void k_init_out_t(const float* __restrict__ bias, float* __restrict__ out_t, int M) {
    const int i = blockIdx.x * blockDim.x + threadIdx.x;
    if (i < M * BATCH) out_t[i] = bias[i >> 5];
}

__global__ void k_scatter(const float* __restrict__ xt, const float* __restrict__ values,
                          const int* __restrict__ idx, float* __restrict__ out_t, int E) {
    const int t = blockIdx.x * blockDim.x + threadIdx.x;
    const int e = t >> 5;
    const int b = t & 31;
    if (e < E) {
        const int src = idx[e];
        const int dst = idx[E + e];
        const float contrib = values[e] * xt[(size_t)src * BATCH + b];
        atomicAdd(&out_t[(size_t)dst * BATCH + b], contrib);
    }
}

// ---- transpose out_t (M,32) -> out (32,M), LDS tiled ----
__global__ void k_transpose_out(const float* __restrict__ out_t, float* __restrict__ out, int M) {
    __shared__ float tile[32][33];
    const int m0 = blockIdx.x * 32;
    const int tx = threadIdx.x;
    const int ty = threadIdx.y;
    #pragma unroll
    for (int k = 0; k < 4; ++k) {
        const int m = m0 + ty + 8 * k;
        if (m < M) tile[ty + 8 * k][tx] = out_t[(size_t)m * BATCH + tx];
    }
    __syncthreads();
    #pragma unroll
    for (int k = 0; k < 4; ++k) {
        const int b = ty + 8 * k;
        const int m = m0 + tx;
        if (m < M) out[(size_t)b * M + m] = tile[tx][b];
    }
}

extern "C" void kernel_launch(void* const* d_in, const int* in_sizes, int n_in,
                              void* d_out, int out_size, void* d_ws, size_t ws_size,
                              hipStream_t stream) {
    const float* x      = (const float*)d_in[0];  // (B,N,1) fp32
    const float* values = (const float*)d_in[1];  // (E,)    fp32
    const float* bias   = (const float*)d_in[2];  // (M,1)   fp32
    const int*   idx    = (const int*)d_in[3];    // (2,E)   int32

    const int N = in_sizes[0] / BATCH;   // 50000
    const int E = in_sizes[3] / 2;       // 1600000
    const int M = in_sizes[2];           // 50000

    float* out = (float*)d_out;

    // ---- workspace carve (512B aligned) ----
    char* base = (char*)d_ws;
    size_t off = 0;
    auto carve = [&](size_t bytes) -> void* {
        void* r = base + off;
        off = (off + bytes + 511) & ~(size_t)511;
        return r;
    };
    float* xt     = (float*)carve((size_t)N * BATCH * sizeof(float));   // 6.4 MB
    float* out_t  = (float*)carve((size_t)M * BATCH * sizeof(float));   // 6.4 MB
    int2*  sv     = (int2*)carve((size_t)E * sizeof(int2));             // 12.8 MB
    int*   counts = (int*)carve((size_t)M * sizeof(int));
    int*   offs   = (int*)carve((size_t)(M + 1) * sizeof(int));
    int*   cursor = (int*)carve((size_t)M * sizeof(int));
    int*   bsums  = (int*)carve(4096);
    int*   bprefix= (int*)carve(4096);
    const size_t csr_needed = off;

    dim3 tblk(32, 8);
    k_transpose_x<<<(N + 31) / 32, tblk, 0, stream>>>(x, xt, N);

    if (csr_needed <= ws_size) {
        const int nb = (M + 1023) / 1024;  // 49
        k_zero_i32<<<(M + 255) / 256, 256, 0, stream>>>(counts, M);
        k_hist<<<(E + 255) / 256, 256, 0, stream>>>(idx, counts, E);
        k_scan_local<<<nb, 1024, 0, stream>>>(counts, offs, bsums, M);
        k_scan_bsums<<<1, 64, 0, stream>>>(bsums, bprefix, offs, nb, M);
        k_scan_add<<<(M + 255) / 256, 256, 0, stream>>>(offs, cursor, bprefix, M);
        k_reorder<<<(E + 255) / 256, 256, 0, stream>>>(idx, values, cursor, sv, E);
        k_gather<<<(M + 3) / 4, 256, 0, stream>>>(sv, offs, xt, bias, out_t, M);
    } else {
        // fallback: proven atomic path
        k_init_out_t<<<(M * BATCH + 255) / 256, 256, 0, stream>>>(bias, out_t, M);
        const long long total = (long long)E * BATCH;
        k_scatter<<<(int)((total + 255) / 256), 256, 0, stream>>>(xt, values, idx, out_t, E);
    }

    k_transpose_out<<<(M + 31) / 32, tblk, 0, stream>>>(out_t, out, M);
}